// Round 5
// baseline (179.089 us; speedup 1.0000x reference)
//
#include <hip/hip_runtime.h>

typedef unsigned short u16;
typedef unsigned int u32;
typedef __attribute__((ext_vector_type(8))) short bf16x8;
typedef __attribute__((ext_vector_type(4))) float f32x4;

#define B_   128
#define P_   2048
#define NC_  10
#define F_   160      // NC*CLO
#define NBLK 512      // k_pass blocks: 2 per CU (proven best occupancy)
#define PPB  4        // p-tiles per block
#define NTHR 512

// async global->LDS (linear dest = wave-uniform base + lane*size)
#define GLL16(g, l) __builtin_amdgcn_global_load_lds( \
    (const __attribute__((address_space(1))) void*)(g), \
    (__attribute__((address_space(3))) void*)(l), 16, 0, 0)
#define GLL4(g, l) __builtin_amdgcn_global_load_lds( \
    (const __attribute__((address_space(1))) void*)(g), \
    (__attribute__((address_space(3))) void*)(l), 4, 0, 0)

__device__ __forceinline__ u16 f2bf(float f) {
    union { float f; unsigned u; } v; v.f = f;
    unsigned r = v.u + 0x7FFFu + ((v.u >> 16) & 1u);   // RNE
    return (u16)(r >> 16);
}
__device__ __forceinline__ float bf2f(u16 h) {
    union { unsigned u; float f; } v; v.u = ((unsigned)h) << 16;
    return v.f;
}

// Fused prep (hardware-validated; SQ_LDS_BANK_CONFLICT=0 downstream).
// Blocks 0..4095: squash along NP=32, bf16-cast, write xb[p][b][chunk] with
// chunk XOR-swizzle (slot' = slot ^ ((b>>1)&3)). Blocks 4096..6143:
// weight[p][k][f] fp32 -> wb[p][f][k] bf16 transpose via LDS, same swizzle.
__global__ void k_prep(const float* __restrict__ t, const float* __restrict__ w,
                       u16* __restrict__ xb, u16* __restrict__ wb) {
    __shared__ u16 wl[32 * F_];
    const int tid = threadIdx.x;
    if (blockIdx.x < 4096) {
        int g = blockIdx.x * 256 + tid;
        int pair = g >> 2, sub = g & 3;
        int p = pair & 2047, b = pair >> 11;
        const float4* tg = (const float4*)t;
        int fi = pair * 8 + sub * 2;
        float4 va = tg[fi], vb = tg[fi + 1];
        float ss = va.x*va.x + va.y*va.y + va.z*va.z + va.w*va.w
                 + vb.x*vb.x + vb.y*vb.y + vb.z*vb.z + vb.w*vb.w;
        ss += __shfl_xor(ss, 1);      // quad holds the full 32-elem sum
        ss += __shfl_xor(ss, 2);
        float fct = ss / ((1.f + ss) * sqrtf(ss));
        u16 h[8] __attribute__((aligned(16)));
        h[0]=f2bf(va.x*fct); h[1]=f2bf(va.y*fct); h[2]=f2bf(va.z*fct); h[3]=f2bf(va.w*fct);
        h[4]=f2bf(vb.x*fct); h[5]=f2bf(vb.y*fct); h[6]=f2bf(vb.z*fct); h[7]=f2bf(vb.w*fct);
        int sw = sub ^ ((b >> 1) & 3);
        *(uint4*)(xb + (p * 128 + b) * 32 + sw * 8) = *(const uint4*)h;
    } else {
        int p = blockIdx.x - 4096;
        const float4* wp = (const float4*)(w + p * 32 * F_);
        for (int e4 = tid; e4 < 1280; e4 += 256) {
            float4 v = wp[e4];
            u16 h[4] __attribute__((aligned(8)));
            h[0]=f2bf(v.x); h[1]=f2bf(v.y); h[2]=f2bf(v.z); h[3]=f2bf(v.w);
            *(ushort4*)(wl + e4 * 4) = *(const ushort4*)h;
        }
        __syncthreads();
        u16* wo = wb + p * F_ * 32;
        for (int sid = tid; sid < 640; sid += 256) {
            int f = sid >> 2, k0 = (sid & 3) << 3;
            u16 tmp[8] __attribute__((aligned(16)));
#pragma unroll
            for (int j = 0; j < 8; ++j) tmp[j] = wl[(k0 + j) * F_ + f];
            int sw = (sid & 3) ^ ((f >> 1) & 3);
            *(uint4*)(wo + f * 32 + sw * 8) = *(const uint4*)tmp;
        }
    }
}

// One routing pass. ALL p-tiles staged upfront via global_load_lds into
// single-use LDS buffers (4 x 18 KB = 72 KB; 2 blocks/CU). Per tile: counted
// s_waitcnt vmcnt(3*(PPB-1-t)) + ONE raw s_barrier -- tiles t+1.. stay in
// flight across barriers (T3/T4); no buffer reuse so no trailing barrier, no
// VGPR staging round-trip. Counts are schedule-robust: after tile t's last
// GLL there are always exactly 3*(PPB-1-t) younger GLLs.
// MODE 0: c=0.1 uniform (MFMA-chained). MODE>=1: logits t = u.vprev (vprev =
// v0 for pass 1, v0+v1 for pass 2 -- bias eliminated algebraically), softmax
// over n, weighted sum.
template<int MODE>
__global__ __launch_bounds__(NTHR, 2) void k_pass(
        const u16* __restrict__ xb, const u16* __restrict__ wb,
        const float* __restrict__ vprev, u16* __restrict__ s_part)
{
    __shared__ u16 xt[PPB][4096];    // 4 x 8 KB
    __shared__ u16 wt[PPB][5120];    // 4 x 10 KB  (72 KB total)
    const int tid = threadIdx.x, blk = blockIdx.x;
    const int L = tid & 63, wv = tid >> 6;
    const int q = L >> 4, col = L & 15;
    const int b = wv * 16 + col;
    const int qs = (q ^ ((col >> 1) & 3)) * 8;   // swizzled k-slot (shorts)
    const int p0 = blk * PPB;

    float4 vv[NC_];
    if (MODE != 0) {
#pragma unroll
        for (int n = 0; n < NC_; ++n)
            vv[n] = *(const float4*)(vprev + b * F_ + n * 16 + q * 4);
    }

    f32x4 s_acc[NC_];
#pragma unroll
    for (int n = 0; n < NC_; ++n) s_acc[n] = (f32x4){0.f, 0.f, 0.f, 0.f};

    // issue ALL tiles' loads upfront: 3 GLL per tile per wave, wave-uniform
#pragma unroll
    for (int t = 0; t < PPB; ++t) {
        const u16* xg_ = xb + (size_t)(p0 + t) * 4096;
        const u16* wg_ = wb + (size_t)(p0 + t) * 5120;
        GLL16(xg_ + tid * 8, &xt[t][tid * 8]);
        GLL16(wg_ + tid * 8, &wt[t][tid * 8]);
        GLL4 (wg_ + 4096 + tid * 2, &wt[t][4096 + tid * 2]);
    }

#pragma unroll
    for (int t = 0; t < PPB; ++t) {
        if (t == 0)      asm volatile("s_waitcnt vmcnt(9)" ::: "memory");
        else if (t == 1) asm volatile("s_waitcnt vmcnt(6)" ::: "memory");
        else if (t == 2) asm volatile("s_waitcnt vmcnt(3)" ::: "memory");
        else             asm volatile("s_waitcnt vmcnt(0)" ::: "memory");
        __builtin_amdgcn_s_barrier();      // tile t visible to all waves

        bf16x8 bfrag = *(const bf16x8*)&xt[t][b * 32 + qs];   // x[b][k=q*8+j]
        if (MODE == 0) {
#pragma unroll
            for (int n = 0; n < NC_; ++n) {
                bf16x8 afrag = *(const bf16x8*)&wt[t][(n * 16 + col) * 32 + qs];
                s_acc[n] = __builtin_amdgcn_mfma_f32_16x16x32_bf16(afrag, bfrag, s_acc[n], 0, 0, 0);
            }
        } else {
            float tt[NC_];
#pragma unroll
            for (int n = 0; n < NC_; ++n) {
                bf16x8 afrag = *(const bf16x8*)&wt[t][(n * 16 + col) * 32 + qs];
                f32x4 z = {0.f, 0.f, 0.f, 0.f};
                f32x4 acc = __builtin_amdgcn_mfma_f32_16x16x32_bf16(afrag, bfrag, z, 0, 0, 0);
                float tv = acc[0]*vv[n].x + acc[1]*vv[n].y + acc[2]*vv[n].z + acc[3]*vv[n].w;
                tv += __shfl_xor(tv, 16);   // full 16-elem dot over k'
                tv += __shfl_xor(tv, 32);
                tt[n] = tv;
            }
            float mx = tt[0];
#pragma unroll
            for (int n = 1; n < NC_; ++n) mx = fmaxf(mx, tt[n]);
            float den = 0.f;
#pragma unroll
            for (int n = 0; n < NC_; ++n) { tt[n] = __expf(tt[n] - mx); den += tt[n]; }
            float inv = 1.f / den;
#pragma unroll
            for (int n = 0; n < NC_; ++n) {
                bf16x8 afrag = *(const bf16x8*)&wt[t][(n * 16 + col) * 32 + qs];
                f32x4 z = {0.f, 0.f, 0.f, 0.f};
                f32x4 acc = __builtin_amdgcn_mfma_f32_16x16x32_bf16(afrag, bfrag, z, 0, 0, 0);
                float cf = tt[n] * inv;
#pragma unroll
                for (int r = 0; r < 4; ++r) s_acc[n][r] += cf * acc[r];
            }
        }
    }

    // n-major partial store: per n, each wave writes 512 contiguous bytes
    // (4 full 128B lines) -> no partial-line RMW.
    u16* sp = s_part + blk * (B_ * F_);
    const float sc = (MODE == 0) ? 0.1f : 1.f;
#pragma unroll
    for (int n = 0; n < NC_; ++n) {
        u16 h[4] __attribute__((aligned(8)));
#pragma unroll
        for (int r = 0; r < 4; ++r) h[r] = f2bf(s_acc[n][r] * sc);
        *(ushort4*)(sp + n * 2048 + b * 16 + q * 4) = *(const ushort4*)h;
    }
}

// Sum bf16 partials over NBLK groups (n-major layout, uint4 = 8 bf16 per
// load), squash along CLO=16. ADD: add vprev (v0+v1 for next pass's logits).
template<int ADD>
__global__ void k_red(const u16* __restrict__ s_part,
                      const float* __restrict__ vprev, float* __restrict__ vout) {
    __shared__ float red[32 * 66];
    const int tid = threadIdx.x, blk = blockIdx.x;
    const int pid = tid & 7, part = tid >> 3;     // 8 uint4 lanes x 32 parts
    const uint4* sp4 = (const uint4*)s_part;      // 2560 uint4 per group
    const int base = blk * 8 + pid;               // uint4 column 0..2559
    float a[8];
#pragma unroll
    for (int j = 0; j < 8; ++j) a[j] = 0.f;
    for (int g = part; g < NBLK; g += 32) {       // 16 iterations
        uint4 uv = sp4[(size_t)g * 2560 + base];
        a[0] += bf2f((u16)(uv.x & 0xffff)); a[1] += bf2f((u16)(uv.x >> 16));
        a[2] += bf2f((u16)(uv.y & 0xffff)); a[3] += bf2f((u16)(uv.y >> 16));
        a[4] += bf2f((u16)(uv.z & 0xffff)); a[5] += bf2f((u16)(uv.z >> 16));
        a[6] += bf2f((u16)(uv.w & 0xffff)); a[7] += bf2f((u16)(uv.w >> 16));
    }
#pragma unroll
    for (int j = 0; j < 8; ++j) red[part * 66 + pid * 8 + j] = a[j];
    __syncthreads();
    if (tid < 32) {
        float s0 = 0.f, s1 = 0.f;
#pragma unroll
        for (int k = 0; k < 32; ++k) {
            s0 += red[k * 66 + tid * 2];
            s1 += red[k * 66 + tid * 2 + 1];
        }
        float sq = s0 * s0 + s1 * s1;
        sq += __shfl_xor(sq, 1);    // 8 lanes = 16 elems of one (b,n) row
        sq += __shfl_xor(sq, 2);
        sq += __shfl_xor(sq, 4);
        float fct = sq / ((1.f + sq) * sqrtf(sq));
        // remap n-major partial column -> b-major output offset
        const int i = blk * 8 + (tid >> 2);        // uint4 column of this pair
        const int n = i >> 8, bb = (i & 255) >> 1, hh = i & 1;
        const int f0 = bb * 160 + n * 16 + hh * 8 + 2 * (tid & 3);
        float2 o = make_float2(s0 * fct, s1 * fct);
        if (ADD) {
            float2 pv = *(const float2*)(vprev + f0);
            o.x += pv.x; o.y += pv.y;
        }
        *(float2*)(vout + f0) = o;
    }
}

extern "C" void kernel_launch(void* const* d_in, const int* in_sizes, int n_in,
                              void* d_out, int out_size, void* d_ws, size_t ws_size,
                              hipStream_t stream) {
    const float* tensor = (const float*)d_in[0];
    const float* weight = (const float*)d_in[1];
    float* out = (float*)d_out;
    char* ws = (char*)d_ws;

    u16*   xb     = (u16*)(ws);                       // 16,777,216 B
    u16*   wb     = (u16*)(ws + 16777216);            // 20,971,520 B
    u16*   s_part = (u16*)(ws + 37748736);            // 512*40960 B = 20,971,520 B
    float* v0     = (float*)(ws + 58720256);          // 81,920 B
    float* vs     = (float*)(ws + 58802176);          // 81,920 B (v0 + v1)

    k_prep<<<6144, 256, 0, stream>>>(tensor, weight, xb, wb);

    k_pass<0><<<NBLK, NTHR, 0, stream>>>(xb, wb, nullptr, s_part);
    k_red<0><<<320, 256, 0, stream>>>(s_part, nullptr, v0);
    k_pass<1><<<NBLK, NTHR, 0, stream>>>(xb, wb, v0, s_part);
    k_red<1><<<320, 256, 0, stream>>>(s_part, v0, vs);
    k_pass<2><<<NBLK, NTHR, 0, stream>>>(xb, wb, vs, s_part);
    k_red<0><<<320, 256, 0, stream>>>(s_part, nullptr, out);
}